// Round 1
// baseline (146.631 us; speedup 1.0000x reference)
//
#include <hip/hip_runtime.h>
#include <stdint.h>

// Problem dims (from reference setup_inputs): B=1, H=W=128, HW=16384, P=128, F=64
#define HW 16384
#define P 128
#define F 64

__global__ __launch_bounds__(P) void weights_kernel(
    const float* __restrict__ sigma,     // [HW][P]
    const float* __restrict__ depth,     // [HW][P]
    const float* __restrict__ rays_dir,  // [HW][3]
    float* __restrict__ out_weights,     // [HW][P]  (sorted-sample order)
    float* __restrict__ out_depth,       // [HW]
    float* __restrict__ out_alpha,       // [HW]
    float* __restrict__ w_orig)          // [HW][P]  scratch: weights in ORIGINAL sample order
{
    const int r   = blockIdx.x;
    const int tid = threadIdx.x;

    __shared__ unsigned long long keys[P];
    __shared__ float ssig[P];
    __shared__ float sds[P];
    __shared__ float sprod[P];
    __shared__ float sred[P];
    __shared__ float sred2[P];

    const float d = depth[r * P + tid];
    ssig[tid] = sigma[r * P + tid];
    // depth is uniform in [0,1) (non-negative) -> float bits are order-preserving.
    // Low 32 bits = original index -> exact stable argsort semantics.
    keys[tid] = ((unsigned long long)__float_as_uint(d) << 32) | (unsigned)tid;
    __syncthreads();

    // Bitonic sort, ascending, 128 elements, 1 elem/thread.
    for (int k = 2; k <= P; k <<= 1) {
        for (int j = k >> 1; j > 0; j >>= 1) {
            const int ixj = tid ^ j;
            if (ixj > tid) {
                const bool up = ((tid & k) == 0);
                const unsigned long long a = keys[tid];
                const unsigned long long b = keys[ixj];
                if ((a > b) == up) { keys[tid] = b; keys[ixj] = a; }
            }
            __syncthreads();
        }
    }

    const unsigned long long kk = keys[tid];
    const int   idx   = (int)(kk & 0xffffffffULL);
    const float dsort = __uint_as_float((unsigned)(kk >> 32));
    sds[tid] = dsort;
    __syncthreads();

    const float dist_z = (tid < P - 1) ? (sds[tid + 1] - dsort) : 1e10f;

    const float rx = rays_dir[r * 3 + 0];
    const float ry = rays_dir[r * 3 + 1];
    const float rz = rays_dir[r * 3 + 2];
    const float rnorm = sqrtf(rx * rx + ry * ry + rz * rz);

    const float sg    = fmaxf(ssig[idx], 0.0f);
    const float t     = expf(-sg * dist_z * rnorm);   // = 1 - alpha
    const float alpha = 1.0f - t;
    const float tp    = (1.0f - alpha) + 1e-10f;      // match ref expression order

    // Inclusive product scan of tp (Hillis-Steele, in-place, double sync).
    sprod[tid] = tp;
    __syncthreads();
    #pragma unroll
    for (int off = 1; off < P; off <<= 1) {
        const float v = (tid >= off) ? sprod[tid - off] : 1.0f;
        __syncthreads();
        sprod[tid] *= v;
        __syncthreads();
    }
    const float trans = (tid == 0) ? 1.0f : sprod[tid - 1];  // exclusive
    const float w = alpha * trans;

    out_weights[r * P + tid] = w;   // sorted order (4th reference output)
    w_orig[r * P + idx]      = w;   // scattered back to original order (for feat pass)

    sred[tid]  = w;
    sred2[tid] = w * dsort;
    __syncthreads();
    #pragma unroll
    for (int off = P / 2; off > 0; off >>= 1) {
        if (tid < off) {
            sred[tid]  += sred[tid + off];
            sred2[tid] += sred2[tid + off];
        }
        __syncthreads();
    }
    if (tid == 0) {
        const float sumw = sred[0];
        float dm = sred2[0] / fmaxf(sumw, 1e-12f);
        dm = (dm - 0.001f) / (1000.0f - 0.001f);
        dm = fminf(fmaxf(dm, 0.0f), 1.0f);
        out_depth[r] = dm;
        out_alpha[r] = sumw;
    }
}

// One wave per ray. lane = psub(2b) | f4(4b): f4 selects a float4 of F=64,
// psub strides the P dimension 4-wide. feat reads are fully coalesced
// (1024 B per wave per iteration, contiguous).
__global__ __launch_bounds__(256) void feat_kernel(
    const float* __restrict__ feat,    // [HW][P][F]
    const float* __restrict__ w_orig,  // [HW][P]  original-order weights
    float* __restrict__ out_feat)      // [F][HW]
{
    const int ray  = blockIdx.x * 4 + (threadIdx.x >> 6);
    const int lane = threadIdx.x & 63;
    const int f4   = lane & 15;   // which float4 chunk of F
    const int psub = lane >> 4;   // 0..3

    const float* wp = w_orig + (size_t)ray * P;
    const float wl0 = wp[lane];
    const float wl1 = wp[64 + lane];

    const float4* fp = (const float4*)(feat + (size_t)ray * P * F);

    float4 acc = make_float4(0.f, 0.f, 0.f, 0.f);
    #pragma unroll
    for (int it = 0; it < P / 4; ++it) {
        const int p = it * 4 + psub;
        const float w = (p < 64) ? __shfl(wl0, p) : __shfl(wl1, p - 64);
        const float4 v = fp[p * (F / 4) + f4];
        acc.x += w * v.x;
        acc.y += w * v.y;
        acc.z += w * v.z;
        acc.w += w * v.w;
    }
    // Reduce over psub (lane bits 4 and 5).
    acc.x += __shfl_xor(acc.x, 16); acc.y += __shfl_xor(acc.y, 16);
    acc.z += __shfl_xor(acc.z, 16); acc.w += __shfl_xor(acc.w, 16);
    acc.x += __shfl_xor(acc.x, 32); acc.y += __shfl_xor(acc.y, 32);
    acc.z += __shfl_xor(acc.z, 32); acc.w += __shfl_xor(acc.w, 32);

    if (psub == 0) {
        const int f = f4 * 4;
        out_feat[(size_t)(f + 0) * HW + ray] = acc.x;
        out_feat[(size_t)(f + 1) * HW + ray] = acc.y;
        out_feat[(size_t)(f + 2) * HW + ray] = acc.z;
        out_feat[(size_t)(f + 3) * HW + ray] = acc.w;
    }
}

extern "C" void kernel_launch(void* const* d_in, const int* in_sizes, int n_in,
                              void* d_out, int out_size, void* d_ws, size_t ws_size,
                              hipStream_t stream) {
    const float* sigma    = (const float*)d_in[0];
    const float* feat     = (const float*)d_in[1];
    const float* depth    = (const float*)d_in[2];
    // d_in[3] = semantic: sorted in the reference but unused in every output.
    const float* rays_dir = (const float*)d_in[4];

    float* out = (float*)d_out;
    // Flat output layout (return order): feat_map[64*16384], depth_map[16384],
    // alpha_map[16384], weights[16384*128]
    float* out_feat    = out;
    float* out_depth   = out + (size_t)F * HW;
    float* out_alpha   = out_depth + HW;
    float* out_weights = out_alpha + HW;

    float* w_orig = (float*)d_ws;  // HW*P floats = 8 MB

    weights_kernel<<<HW, P, 0, stream>>>(sigma, depth, rays_dir,
                                         out_weights, out_depth, out_alpha, w_orig);
    feat_kernel<<<HW / 4, 256, 0, stream>>>(feat, w_orig, out_feat);
}

// Round 2
// 116.309 us; speedup vs baseline: 1.2607x; 1.2607x over previous
//
#include <hip/hip_runtime.h>
#include <stdint.h>

// Problem dims: B=1, H=W=128, HW=16384, P=128, F=64
#define HW 16384
#define P 128
#define F 64

__global__ __launch_bounds__(256) void nerf_fused_kernel(
    const float* __restrict__ sigma,     // [HW][P]
    const float* __restrict__ feat,      // [HW][P][F]
    const float* __restrict__ depth,     // [HW][P]
    const float* __restrict__ rays_dir,  // [HW][3]
    float* __restrict__ out_feat,        // [F][HW]
    float* __restrict__ out_depth,       // [HW]
    float* __restrict__ out_alpha,       // [HW]
    float* __restrict__ out_weights)     // [HW][P] (sorted-sample order)
{
    const int r    = blockIdx.x;
    const int tid  = threadIdx.x;
    const int lane = tid & 63;
    const int wv   = tid >> 6;

    __shared__ unsigned long long skey[P];
    __shared__ float  sdep[P];      // sorted depth
    __shared__ float  ssig[P];      // sorted sigma
    __shared__ int    sidx[P];      // sorted pos -> original idx
    __shared__ float  sw[P];        // weights in ORIGINAL sample order
    __shared__ float  swave[8];     // cross-wave scan/reduce scratch
    __shared__ float4 spart[4][16]; // cross-wave feat partials

    // ---- load + build stable sort keys (depth in [0,1) -> bits monotonic) ----
    float myd = 0.f, mysig = 0.f;
    if (tid < P) {
        myd   = depth[r * P + tid];
        mysig = sigma[r * P + tid];
        skey[tid] = ((unsigned long long)__float_as_uint(myd) << 32) | (unsigned)tid;
    }
    __syncthreads();

    // ---- O(P) rank sort: unique ranks (idx tie-break) -> race-free scatter ----
    if (tid < P) {
        const unsigned long long mk = skey[tid];
        int rank = 0;
        #pragma unroll 8
        for (int j = 0; j < P; ++j) rank += (skey[j] < mk) ? 1 : 0;
        sdep[rank] = myd;
        ssig[rank] = mysig;
        sidx[rank] = tid;
    }
    __syncthreads();

    // ---- alpha at sorted position p = tid (tid < 128) ----
    float tp = 1.0f, alpha = 0.f, dsort = 0.f;
    if (tid < P) {
        dsort = sdep[tid];
        const float dz = (tid < P - 1) ? (sdep[tid + 1] - dsort) : 1e10f;
        const float rx = rays_dir[r * 3 + 0];
        const float ry = rays_dir[r * 3 + 1];
        const float rz = rays_dir[r * 3 + 2];
        const float rn = sqrtf(rx * rx + ry * ry + rz * rz);
        const float sg = fmaxf(ssig[tid], 0.0f);
        const float t  = expf(-sg * dz * rn);
        alpha = 1.0f - t;
        tp = (1.0f - alpha) + 1e-10f;   // match ref expression order
    }

    // ---- inclusive product scan via shfl (waves 0,1 carry real data) ----
    float scan = tp;
    #pragma unroll
    for (int off = 1; off < 64; off <<= 1) {
        const float v = __shfl_up(scan, off);
        if (lane >= off) scan *= v;
    }
    if (lane == 63 && wv < 2) swave[wv] = scan;   // wave totals
    __syncthreads();

    if (tid < P) {
        float excl = __shfl_up(scan, 1);
        if (lane == 0) excl = 1.0f;
        if (wv == 1) excl *= swave[0];            // prepend wave-0 product
        const float w = alpha * excl;

        out_weights[r * P + tid] = w;             // sorted order (output 4)
        sw[sidx[tid]] = w;                        // original order (LDS only)

        // reductions: sum(w), sum(w * depth_sorted); w >= 0 so |w| = w
        float s1 = w, s2 = w * dsort;
        #pragma unroll
        for (int off = 32; off > 0; off >>= 1) {
            s1 += __shfl_xor(s1, off);
            s2 += __shfl_xor(s2, off);
        }
        if (lane == 0) { swave[2 + wv * 2] = s1; swave[3 + wv * 2] = s2; }
    }
    __syncthreads();   // sw + swave ready

    if (tid == 0) {
        const float sumw  = swave[2] + swave[4];
        const float sumwd = swave[3] + swave[5];
        float dm = sumwd / fmaxf(sumw, 1e-12f);
        dm = (dm - 0.001f) / (1000.0f - 0.001f);
        dm = fminf(fmaxf(dm, 0.0f), 1.0f);
        out_depth[r] = dm;
        out_alpha[r] = sumw;
    }

    // ---- feat accumulation: all 256 threads, 4 KB contiguous per iter ----
    const int f4 = tid & 15;   // float4 chunk of F
    const int ps = tid >> 4;   // 0..15, strides P
    const float4* fp = (const float4*)(feat + (size_t)r * P * F);

    float4 acc = make_float4(0.f, 0.f, 0.f, 0.f);
    #pragma unroll
    for (int it = 0; it < P / 16; ++it) {        // 8 iterations
        const int p = it * 16 + ps;
        const float w  = sw[p];                  // 16-thread broadcast read
        const float4 v = fp[p * (F / 4) + f4];
        acc.x += w * v.x;
        acc.y += w * v.y;
        acc.z += w * v.z;
        acc.w += w * v.w;
    }
    // reduce over intra-wave part of ps (lane bits 4,5)
    acc.x += __shfl_xor(acc.x, 16); acc.y += __shfl_xor(acc.y, 16);
    acc.z += __shfl_xor(acc.z, 16); acc.w += __shfl_xor(acc.w, 16);
    acc.x += __shfl_xor(acc.x, 32); acc.y += __shfl_xor(acc.y, 32);
    acc.z += __shfl_xor(acc.z, 32); acc.w += __shfl_xor(acc.w, 32);

    if ((lane >> 4) == 0) spart[wv][f4] = acc;   // lanes 0..15 hold group sums
    __syncthreads();

    if (tid < 16) {
        const float4 a0 = spart[0][tid];
        const float4 a1 = spart[1][tid];
        const float4 a2 = spart[2][tid];
        const float4 a3 = spart[3][tid];
        const int f = tid * 4;
        out_feat[(size_t)(f + 0) * HW + r] = a0.x + a1.x + a2.x + a3.x;
        out_feat[(size_t)(f + 1) * HW + r] = a0.y + a1.y + a2.y + a3.y;
        out_feat[(size_t)(f + 2) * HW + r] = a0.z + a1.z + a2.z + a3.z;
        out_feat[(size_t)(f + 3) * HW + r] = a0.w + a1.w + a2.w + a3.w;
    }
}

extern "C" void kernel_launch(void* const* d_in, const int* in_sizes, int n_in,
                              void* d_out, int out_size, void* d_ws, size_t ws_size,
                              hipStream_t stream) {
    const float* sigma    = (const float*)d_in[0];
    const float* feat     = (const float*)d_in[1];
    const float* depth    = (const float*)d_in[2];
    // d_in[3] = semantic: sorted in the reference but unused in every output.
    const float* rays_dir = (const float*)d_in[4];

    float* out = (float*)d_out;
    // Flat output layout (return order): feat_map[64*16384], depth_map[16384],
    // alpha_map[16384], weights[16384*128]
    float* out_feat    = out;
    float* out_depth   = out + (size_t)F * HW;
    float* out_alpha   = out_depth + HW;
    float* out_weights = out_alpha + HW;

    nerf_fused_kernel<<<HW, 256, 0, stream>>>(sigma, feat, depth, rays_dir,
                                              out_feat, out_depth, out_alpha,
                                              out_weights);
}

// Round 3
// 111.980 us; speedup vs baseline: 1.3094x; 1.0387x over previous
//
#include <hip/hip_runtime.h>
#include <stdint.h>

// Problem dims: B=1, H=W=128, HW=16384, P=128, F=64
#define HW 16384
#define P 128
#define F 64

__global__ __launch_bounds__(256) void nerf_fused_kernel(
    const float* __restrict__ sigma,     // [HW][P]
    const float* __restrict__ feat,      // [HW][P][F]
    const float* __restrict__ depth,     // [HW][P]
    const float* __restrict__ rays_dir,  // [HW][3]
    float* __restrict__ out_feat,        // [F][HW]
    float* __restrict__ out_depth,       // [HW]
    float* __restrict__ out_alpha,       // [HW]
    float* __restrict__ out_weights)     // [HW][P] (sorted-sample order)
{
    const int r    = blockIdx.x;
    const int tid  = threadIdx.x;
    const int lane = tid & 63;
    const int wv   = tid >> 6;

    __shared__ unsigned long long skey[P];
    __shared__ float  sdep[P];      // sorted depth
    __shared__ float  ssig[P];      // sorted sigma
    __shared__ int    sidx[P];      // sorted pos -> original idx
    __shared__ float  sw[P];        // weights in ORIGINAL sample order
    __shared__ float  swave[8];     // cross-wave scan/reduce scratch
    __shared__ float4 spart[4][16]; // cross-wave feat partials

    // ---- prologue-critical loads FIRST (oldest in the vmcnt queue, so the
    // prologue's waits are counted and leave the feat tile in flight) ----
    float myd = 0.f, mysig = 0.f;
    if (tid < P) {
        myd   = depth[r * P + tid];
        mysig = sigma[r * P + tid];
    }
    const float rx = rays_dir[r * 3 + 0];
    const float ry = rays_dir[r * 3 + 1];
    const float rz = rays_dir[r * 3 + 2];

    // Pin issue order: nothing below may be hoisted above this point.
    __builtin_amdgcn_sched_barrier(0);

    // ---- issue the whole 32 KB feat tile now; consumed after the prologue ----
    const int f4 = tid & 15;   // float4 chunk of F
    const int ps = tid >> 4;   // 0..15, strides P
    const float4* fp = (const float4*)(feat + (size_t)r * P * F);
    float4 fv[8];
    #pragma unroll
    for (int it = 0; it < 8; ++it)
        fv[it] = fp[(it * 16 + ps) * (F / 4) + f4];

    // ---- stable sort keys (depth in [0,1) -> float bits order-preserving) ----
    if (tid < P)
        skey[tid] = ((unsigned long long)__float_as_uint(myd) << 32) | (unsigned)tid;
    __syncthreads();

    // ---- O(P) rank sort: unique ranks (idx tie-break) -> race-free scatter ----
    if (tid < P) {
        const unsigned long long mk = skey[tid];
        int rank = 0;
        #pragma unroll 8
        for (int j = 0; j < P; ++j) rank += (skey[j] < mk) ? 1 : 0;
        sdep[rank] = myd;
        ssig[rank] = mysig;
        sidx[rank] = tid;
    }
    __syncthreads();

    // ---- alpha at sorted position p = tid (tid < 128) ----
    float tp = 1.0f, alpha = 0.f, dsort = 0.f;
    if (tid < P) {
        dsort = sdep[tid];
        const float dz = (tid < P - 1) ? (sdep[tid + 1] - dsort) : 1e10f;
        const float rn = sqrtf(rx * rx + ry * ry + rz * rz);
        const float sg = fmaxf(ssig[tid], 0.0f);
        const float t  = expf(-sg * dz * rn);
        alpha = 1.0f - t;
        tp = (1.0f - alpha) + 1e-10f;   // match ref expression order
    }

    // ---- inclusive product scan via shfl (waves 0,1 carry real data) ----
    float scan = tp;
    #pragma unroll
    for (int off = 1; off < 64; off <<= 1) {
        const float v = __shfl_up(scan, off);
        if (lane >= off) scan *= v;
    }
    if (lane == 63 && wv < 2) swave[wv] = scan;   // wave totals
    __syncthreads();

    if (tid < P) {
        float excl = __shfl_up(scan, 1);
        if (lane == 0) excl = 1.0f;
        if (wv == 1) excl *= swave[0];            // prepend wave-0 product
        const float w = alpha * excl;

        out_weights[r * P + tid] = w;             // sorted order (output 4)
        sw[sidx[tid]] = w;                        // original order (LDS only)

        // reductions: sum(w), sum(w * depth_sorted); w >= 0 so |w| = w
        float s1 = w, s2 = w * dsort;
        #pragma unroll
        for (int off = 32; off > 0; off >>= 1) {
            s1 += __shfl_xor(s1, off);
            s2 += __shfl_xor(s2, off);
        }
        if (lane == 0) { swave[2 + wv * 2] = s1; swave[3 + wv * 2] = s2; }
    }
    __syncthreads();   // sw + swave ready

    if (tid == 0) {
        const float sumw  = swave[2] + swave[4];
        const float sumwd = swave[3] + swave[5];
        float dm = sumwd / fmaxf(sumw, 1e-12f);
        dm = (dm - 0.001f) / (1000.0f - 0.001f);
        dm = fminf(fmaxf(dm, 0.0f), 1.0f);
        out_depth[r] = dm;
        out_alpha[r] = sumw;
    }

    // ---- feat accumulation from the in-flight tile ----
    float4 acc = make_float4(0.f, 0.f, 0.f, 0.f);
    #pragma unroll
    for (int it = 0; it < 8; ++it) {
        const float w = sw[it * 16 + ps];        // broadcast read
        acc.x += w * fv[it].x;
        acc.y += w * fv[it].y;
        acc.z += w * fv[it].z;
        acc.w += w * fv[it].w;
    }
    // reduce over intra-wave part of ps (lane bits 4,5)
    acc.x += __shfl_xor(acc.x, 16); acc.y += __shfl_xor(acc.y, 16);
    acc.z += __shfl_xor(acc.z, 16); acc.w += __shfl_xor(acc.w, 16);
    acc.x += __shfl_xor(acc.x, 32); acc.y += __shfl_xor(acc.y, 32);
    acc.z += __shfl_xor(acc.z, 32); acc.w += __shfl_xor(acc.w, 32);

    if ((lane >> 4) == 0) spart[wv][f4] = acc;   // lanes 0..15 hold group sums
    __syncthreads();

    if (tid < 16) {
        const float4 a0 = spart[0][tid];
        const float4 a1 = spart[1][tid];
        const float4 a2 = spart[2][tid];
        const float4 a3 = spart[3][tid];
        const int f = tid * 4;
        out_feat[(size_t)(f + 0) * HW + r] = a0.x + a1.x + a2.x + a3.x;
        out_feat[(size_t)(f + 1) * HW + r] = a0.y + a1.y + a2.y + a3.y;
        out_feat[(size_t)(f + 2) * HW + r] = a0.z + a1.z + a2.z + a3.z;
        out_feat[(size_t)(f + 3) * HW + r] = a0.w + a1.w + a2.w + a3.w;
    }
}

extern "C" void kernel_launch(void* const* d_in, const int* in_sizes, int n_in,
                              void* d_out, int out_size, void* d_ws, size_t ws_size,
                              hipStream_t stream) {
    const float* sigma    = (const float*)d_in[0];
    const float* feat     = (const float*)d_in[1];
    const float* depth    = (const float*)d_in[2];
    // d_in[3] = semantic: sorted in the reference but unused in every output.
    const float* rays_dir = (const float*)d_in[4];

    float* out = (float*)d_out;
    // Flat output layout (return order): feat_map[64*16384], depth_map[16384],
    // alpha_map[16384], weights[16384*128]
    float* out_feat    = out;
    float* out_depth   = out + (size_t)F * HW;
    float* out_alpha   = out_depth + HW;
    float* out_weights = out_alpha + HW;

    nerf_fused_kernel<<<HW, 256, 0, stream>>>(sigma, feat, depth, rays_dir,
                                              out_feat, out_depth, out_alpha,
                                              out_weights);
}

// Round 4
// 111.850 us; speedup vs baseline: 1.3110x; 1.0012x over previous
//
#include <hip/hip_runtime.h>
#include <stdint.h>

// Problem dims: B=1, H=W=128, HW=16384, P=128, F=64
#define HW 16384
#define P 128
#define F 64

// Raw workgroup barrier WITHOUT the vmcnt(0) drain that __syncthreads emits.
// LDS ordering only: producer-side lgkmcnt(0) + compiler/scheduler fences.
// (Pattern per the 8-phase template; rule #18: sched_barrier after asm waits.)
#define BAR_LDS()                                            \
    do {                                                     \
        asm volatile("s_waitcnt lgkmcnt(0)" ::: "memory");   \
        __builtin_amdgcn_sched_barrier(0);                   \
        __builtin_amdgcn_s_barrier();                        \
        __builtin_amdgcn_sched_barrier(0);                   \
        asm volatile("" ::: "memory");                       \
    } while (0)

__global__ __launch_bounds__(256) void nerf_fused_kernel(
    const float* __restrict__ sigma,     // [HW][P]
    const float* __restrict__ feat,      // [HW][P][F]
    const float* __restrict__ depth,     // [HW][P]
    const float* __restrict__ rays_dir,  // [HW][3]
    float* __restrict__ out_feat,        // [F][HW]
    float* __restrict__ out_depth,       // [HW]
    float* __restrict__ out_alpha,       // [HW]
    float* __restrict__ out_weights)     // [HW][P] (sorted-sample order)
{
    const int r    = blockIdx.x;
    const int tid  = threadIdx.x;
    const int lane = tid & 63;
    const int wv   = tid >> 6;

    __shared__ unsigned long long skey[P];
    __shared__ float  sdep[P];      // sorted depth
    __shared__ float  ssig[P];      // sorted sigma
    __shared__ int    sidx[P];      // sorted pos -> original idx
    __shared__ float  sw[P];        // weights in ORIGINAL sample order
    __shared__ float  swave[8];     // cross-wave scan/reduce scratch
    __shared__ float4 spart[4][16]; // cross-wave feat partials

    // ---- prologue-critical loads FIRST (oldest in the vmcnt queue) ----
    float myd = 0.f, mysig = 0.f;
    if (tid < P) {
        myd   = depth[r * P + tid];
        mysig = sigma[r * P + tid];
    }
    const float rx = rays_dir[r * 3 + 0];
    const float ry = rays_dir[r * 3 + 1];
    const float rz = rays_dir[r * 3 + 2];

    // Pin issue order: nothing below may be hoisted above this point.
    __builtin_amdgcn_sched_barrier(0);

    // ---- issue the whole 32 KB feat tile; stays in flight through the
    // prologue because BAR_LDS() never drains vmcnt ----
    const int f4 = tid & 15;   // float4 chunk of F
    const int ps = tid >> 4;   // 0..15, strides P
    const float4* fp = (const float4*)(feat + (size_t)r * P * F);
    float4 fv[8];
    #pragma unroll
    for (int it = 0; it < 8; ++it)
        fv[it] = fp[(it * 16 + ps) * (F / 4) + f4];

    // ---- stable sort keys (depth in [0,1) -> float bits order-preserving) ----
    if (tid < P)
        skey[tid] = ((unsigned long long)__float_as_uint(myd) << 32) | (unsigned)tid;
    BAR_LDS();

    // ---- O(P) rank sort: unique ranks (idx tie-break) -> race-free scatter ----
    if (tid < P) {
        const unsigned long long mk = skey[tid];
        int rank = 0;
        #pragma unroll 8
        for (int j = 0; j < P; ++j) rank += (skey[j] < mk) ? 1 : 0;
        sdep[rank] = myd;
        ssig[rank] = mysig;
        sidx[rank] = tid;
    }
    BAR_LDS();

    // ---- alpha at sorted position p = tid (tid < 128) ----
    float tp = 1.0f, alpha = 0.f, dsort = 0.f;
    if (tid < P) {
        dsort = sdep[tid];
        const float dz = (tid < P - 1) ? (sdep[tid + 1] - dsort) : 1e10f;
        const float rn = sqrtf(rx * rx + ry * ry + rz * rz);
        const float sg = fmaxf(ssig[tid], 0.0f);
        const float t  = expf(-sg * dz * rn);
        alpha = 1.0f - t;
        tp = (1.0f - alpha) + 1e-10f;   // match ref expression order
    }

    // ---- inclusive product scan via shfl (waves 0,1 carry real data) ----
    float scan = tp;
    #pragma unroll
    for (int off = 1; off < 64; off <<= 1) {
        const float v = __shfl_up(scan, off);
        if (lane >= off) scan *= v;
    }
    if (lane == 63 && wv < 2) swave[wv] = scan;   // wave totals
    BAR_LDS();

    if (tid < P) {
        float excl = __shfl_up(scan, 1);
        if (lane == 0) excl = 1.0f;
        if (wv == 1) excl *= swave[0];            // prepend wave-0 product
        const float w = alpha * excl;

        out_weights[r * P + tid] = w;             // sorted order (output 4)
        sw[sidx[tid]] = w;                        // original order (LDS only)

        // reductions: sum(w), sum(w * depth_sorted); w >= 0 so |w| = w
        float s1 = w, s2 = w * dsort;
        #pragma unroll
        for (int off = 32; off > 0; off >>= 1) {
            s1 += __shfl_xor(s1, off);
            s2 += __shfl_xor(s2, off);
        }
        if (lane == 0) { swave[2 + wv * 2] = s1; swave[3 + wv * 2] = s2; }
    }
    BAR_LDS();   // sw + swave ready

    if (tid == 0) {
        const float sumw  = swave[2] + swave[4];
        const float sumwd = swave[3] + swave[5];
        float dm = sumwd / fmaxf(sumw, 1e-12f);
        dm = (dm - 0.001f) / (1000.0f - 0.001f);
        dm = fminf(fmaxf(dm, 0.0f), 1.0f);
        out_depth[r] = dm;
        out_alpha[r] = sumw;
    }

    // ---- feat accumulation from the in-flight tile (counted vmcnt waits,
    // emitted by the compiler per fv[it] use, consume loads in issue order) ----
    float4 acc = make_float4(0.f, 0.f, 0.f, 0.f);
    #pragma unroll
    for (int it = 0; it < 8; ++it) {
        const float w = sw[it * 16 + ps];        // broadcast read
        acc.x += w * fv[it].x;
        acc.y += w * fv[it].y;
        acc.z += w * fv[it].z;
        acc.w += w * fv[it].w;
    }
    // reduce over intra-wave part of ps (lane bits 4,5)
    acc.x += __shfl_xor(acc.x, 16); acc.y += __shfl_xor(acc.y, 16);
    acc.z += __shfl_xor(acc.z, 16); acc.w += __shfl_xor(acc.w, 16);
    acc.x += __shfl_xor(acc.x, 32); acc.y += __shfl_xor(acc.y, 32);
    acc.z += __shfl_xor(acc.z, 32); acc.w += __shfl_xor(acc.w, 32);

    if ((lane >> 4) == 0) spart[wv][f4] = acc;   // lanes 0..15 hold group sums
    __syncthreads();   // all loads consumed; full drain harmless here

    if (tid < 16) {
        const float4 a0 = spart[0][tid];
        const float4 a1 = spart[1][tid];
        const float4 a2 = spart[2][tid];
        const float4 a3 = spart[3][tid];
        const int f = tid * 4;
        out_feat[(size_t)(f + 0) * HW + r] = a0.x + a1.x + a2.x + a3.x;
        out_feat[(size_t)(f + 1) * HW + r] = a0.y + a1.y + a2.y + a3.y;
        out_feat[(size_t)(f + 2) * HW + r] = a0.z + a1.z + a2.z + a3.z;
        out_feat[(size_t)(f + 3) * HW + r] = a0.w + a1.w + a2.w + a3.w;
    }
}

extern "C" void kernel_launch(void* const* d_in, const int* in_sizes, int n_in,
                              void* d_out, int out_size, void* d_ws, size_t ws_size,
                              hipStream_t stream) {
    const float* sigma    = (const float*)d_in[0];
    const float* feat     = (const float*)d_in[1];
    const float* depth    = (const float*)d_in[2];
    // d_in[3] = semantic: sorted in the reference but unused in every output.
    const float* rays_dir = (const float*)d_in[4];

    float* out = (float*)d_out;
    // Flat output layout (return order): feat_map[64*16384], depth_map[16384],
    // alpha_map[16384], weights[16384*128]
    float* out_feat    = out;
    float* out_depth   = out + (size_t)F * HW;
    float* out_alpha   = out_depth + HW;
    float* out_weights = out_alpha + HW;

    nerf_fused_kernel<<<HW, 256, 0, stream>>>(sigma, feat, depth, rays_dir,
                                              out_feat, out_depth, out_alpha,
                                              out_weights);
}

// Round 5
// 60.882 us; speedup vs baseline: 2.4085x; 1.8372x over previous
//
#include <hip/hip_runtime.h>
#include <stdint.h>

// Problem dims: B=1, H=W=128, HW=16384, P=128, F=64
#define HW 16384
#define P 128
#define F 64

__global__ __launch_bounds__(256) void nerf_fused_kernel(
    const float* __restrict__ sigma,     // [HW][P]
    const float* __restrict__ feat,      // [HW][P][F]
    const float* __restrict__ depth,     // [HW][P]
    const float* __restrict__ rays_dir,  // [HW][3]
    float* __restrict__ out_feat,        // [F][HW]
    float* __restrict__ out_depth,       // [HW]
    float* __restrict__ out_alpha,       // [HW]
    float* __restrict__ out_weights)     // [HW][P] (sorted-sample order)
{
    const int r    = blockIdx.x;
    const int tid  = threadIdx.x;
    const int lane = tid & 63;
    const int wv   = tid >> 6;

    __shared__ unsigned long long skey[P];
    __shared__ float  sdep[P];      // sorted depth
    __shared__ float  ssig[P];      // sorted sigma
    __shared__ int    sidx[P];      // sorted pos -> original idx
    __shared__ float  sw[P];        // weights in ORIGINAL sample order
    __shared__ int    srank[256];   // split rank-count partials
    __shared__ int    plist[P];     // compacted original indices with w != 0
    __shared__ unsigned long long smask[2];
    __shared__ float  swave[8];     // cross-wave scan/reduce scratch
    __shared__ float4 spart[4][16]; // cross-wave feat partials

    // ---- prologue loads ----
    float myd = 0.f, mysig = 0.f;
    if (tid < P) {
        myd   = depth[r * P + tid];
        mysig = sigma[r * P + tid];
    }
    const float rx = rays_dir[r * 3 + 0];
    const float ry = rays_dir[r * 3 + 1];
    const float rz = rays_dir[r * 3 + 2];

    // ---- stable sort keys (depth in [0,1) -> float bits order-preserving) ----
    if (tid < P)
        skey[tid] = ((unsigned long long)__float_as_uint(myd) << 32) | (unsigned)tid;
    __syncthreads();

    // ---- O(P) rank sort, comparisons split across all 256 threads ----
    {
        const int k  = tid & (P - 1);
        const int jb = (tid >> 7) << 6;      // 0 for waves 0-1, 64 for waves 2-3
        const unsigned long long mk = skey[k];
        int rk = 0;
        #pragma unroll 16
        for (int j = 0; j < 64; ++j)
            rk += (skey[jb + j] < mk) ? 1 : 0;
        srank[tid] = rk;
    }
    __syncthreads();
    if (tid < P) {
        const int rank = srank[tid] + srank[tid + P];  // unique (idx tie-break)
        sdep[rank] = myd;
        ssig[rank] = mysig;
        sidx[rank] = tid;
    }
    __syncthreads();

    // ---- alpha at sorted position p = tid (tid < 128) ----
    float tp = 1.0f, alpha = 0.f, dsort = 0.f;
    if (tid < P) {
        dsort = sdep[tid];
        const float dz = (tid < P - 1) ? (sdep[tid + 1] - dsort) : 1e10f;
        const float rn = sqrtf(rx * rx + ry * ry + rz * rz);
        const float sg = fmaxf(ssig[tid], 0.0f);
        alpha = 1.0f - expf(-sg * dz * rn);
        tp = (1.0f - alpha) + 1e-10f;   // match ref expression order
    }

    // ---- inclusive product scan via shfl (waves 0,1 carry real data) ----
    float scan = tp;
    #pragma unroll
    for (int off = 1; off < 64; off <<= 1) {
        const float v = __shfl_up(scan, off);
        if (lane >= off) scan *= v;
    }
    if (lane == 63 && wv < 2) swave[wv] = scan;   // wave totals
    __syncthreads();

    float w = 0.f;
    int   myoff = 0;
    if (tid < P) {
        float excl = __shfl_up(scan, 1);
        if (lane == 0) excl = 1.0f;
        if (wv == 1) excl *= swave[0];            // prepend wave-0 product
        w = alpha * excl;

        out_weights[r * P + tid] = w;             // sorted order (output 4)
        sw[sidx[tid]] = w;                        // original order (LDS only)

        // nonzero-weight ballot (exact: w==0 contributes exactly 0 to feat)
        const unsigned long long mask = __ballot(w != 0.0f);
        if (lane == 0) smask[wv] = mask;
        myoff = (int)__popcll(mask & ((1ull << lane) - 1ull));

        // reductions: sum(w), sum(w * depth_sorted); w >= 0 so |w| = w
        float s1 = w, s2 = w * dsort;
        #pragma unroll
        for (int off = 32; off > 0; off >>= 1) {
            s1 += __shfl_xor(s1, off);
            s2 += __shfl_xor(s2, off);
        }
        if (lane == 0) { swave[2 + wv * 2] = s1; swave[3 + wv * 2] = s2; }
    }
    __syncthreads();   // sw + swave + smask ready

    const int M = (int)(__popcll(smask[0]) + __popcll(smask[1]));

    if (tid < P && w != 0.0f) {
        const int rank = myoff + ((wv == 1) ? (int)__popcll(smask[0]) : 0);
        plist[rank] = sidx[tid];                  // compacted original indices
    }

    if (tid == 0) {
        const float sumw  = swave[2] + swave[4];
        const float sumwd = swave[3] + swave[5];
        float dm = sumwd / fmaxf(sumw, 1e-12f);
        dm = (dm - 0.001f) / (1000.0f - 0.001f);
        dm = fminf(fmaxf(dm, 0.0f), 1.0f);
        out_depth[r] = dm;
        out_alpha[r] = sumw;
    }
    __syncthreads();   // plist ready

    // ---- feat accumulation over nonzero-weight rows only ----
    const int f4 = tid & 15;   // float4 chunk of F
    const int ps = tid >> 4;   // 0..15, strides compacted list
    const float4* fp = (const float4*)(feat + (size_t)r * P * F);

    const int jcap = (M > 0) ? (M - 1) : 0;
    int   pj[8];
    float wj[8];
    #pragma unroll
    for (int i = 0; i < 8; ++i) {
        const int idx = i * 16 + ps;
        const int j   = (idx < M) ? idx : jcap;   // clamp: valid row, w forced 0
        const int p   = plist[j] & (P - 1);       // garbage-safe if M == 0
        pj[i] = p;
        wj[i] = (idx < M) ? sw[p] : 0.0f;
    }

    float4 fv[8];
    #pragma unroll
    for (int i = 0; i < 8; ++i)                   // 8 independent loads, back-to-back
        fv[i] = fp[pj[i] * (F / 4) + f4];

    float4 acc = make_float4(0.f, 0.f, 0.f, 0.f);
    #pragma unroll
    for (int i = 0; i < 8; ++i) {
        acc.x += wj[i] * fv[i].x;
        acc.y += wj[i] * fv[i].y;
        acc.z += wj[i] * fv[i].z;
        acc.w += wj[i] * fv[i].w;
    }
    // reduce over intra-wave part of ps (lane bits 4,5)
    acc.x += __shfl_xor(acc.x, 16); acc.y += __shfl_xor(acc.y, 16);
    acc.z += __shfl_xor(acc.z, 16); acc.w += __shfl_xor(acc.w, 16);
    acc.x += __shfl_xor(acc.x, 32); acc.y += __shfl_xor(acc.y, 32);
    acc.z += __shfl_xor(acc.z, 32); acc.w += __shfl_xor(acc.w, 32);

    if ((lane >> 4) == 0) spart[wv][f4] = acc;   // lanes 0..15 hold group sums
    __syncthreads();

    if (tid < 16) {
        const float4 a0 = spart[0][tid];
        const float4 a1 = spart[1][tid];
        const float4 a2 = spart[2][tid];
        const float4 a3 = spart[3][tid];
        const int f = tid * 4;
        out_feat[(size_t)(f + 0) * HW + r] = a0.x + a1.x + a2.x + a3.x;
        out_feat[(size_t)(f + 1) * HW + r] = a0.y + a1.y + a2.y + a3.y;
        out_feat[(size_t)(f + 2) * HW + r] = a0.z + a1.z + a2.z + a3.z;
        out_feat[(size_t)(f + 3) * HW + r] = a0.w + a1.w + a2.w + a3.w;
    }
}

extern "C" void kernel_launch(void* const* d_in, const int* in_sizes, int n_in,
                              void* d_out, int out_size, void* d_ws, size_t ws_size,
                              hipStream_t stream) {
    const float* sigma    = (const float*)d_in[0];
    const float* feat     = (const float*)d_in[1];
    const float* depth    = (const float*)d_in[2];
    // d_in[3] = semantic: sorted in the reference but unused in every output.
    const float* rays_dir = (const float*)d_in[4];

    float* out = (float*)d_out;
    // Flat output layout (return order): feat_map[64*16384], depth_map[16384],
    // alpha_map[16384], weights[16384*128]
    float* out_feat    = out;
    float* out_depth   = out + (size_t)F * HW;
    float* out_alpha   = out_depth + HW;
    float* out_weights = out_alpha + HW;

    nerf_fused_kernel<<<HW, 256, 0, stream>>>(sigma, feat, depth, rays_dir,
                                              out_feat, out_depth, out_alpha,
                                              out_weights);
}